// Round 23
// baseline (76.089 us; speedup 1.0000x reference)
//
#include <hip/hip_runtime.h>
#include <hip/hip_bf16.h>

typedef __bf16 bf16x8 __attribute__((ext_vector_type(8)));
typedef __bf16 bf16x4 __attribute__((ext_vector_type(4)));
typedef float  f32x4  __attribute__((ext_vector_type(4)));
typedef _Float16 f16x8 __attribute__((ext_vector_type(8)));
typedef _Float16 f16x4 __attribute__((ext_vector_type(4)));

#define MFMA16(a, b, c) __builtin_amdgcn_mfma_f32_16x16x32_bf16(a, b, c, 0, 0, 0)

__device__ __forceinline__ float lrelu(float v) { return fmaxf(v, 0.01f * v); }

// ---------------------------------------------------------------------------
// fused prep kernel (512 thr): b<32 w1s/b1->f16 ; b<288 w2t ; b<544 pw2->w2f
// fragment-major ; b<800 weff (d-split x2)
// ---------------------------------------------------------------------------
__global__ __launch_bounds__(512) void vg_prep(
    const float* __restrict__ lw1, const float* __restrict__ b1,
    const float* __restrict__ lw2, const float* __restrict__ pw2,
    const float* __restrict__ emb, const float* __restrict__ pw1,
    _Float16* __restrict__ w1sh, _Float16* __restrict__ b1h,
    __bf16* __restrict__ w2t, __bf16* __restrict__ w2f,
    __bf16* __restrict__ weffQ) {
  __shared__ float tile[64][65];  // 16640B; weff reuses as es(1024)+red(2048)
  const int b = blockIdx.x, t = threadIdx.x;
  if (b < 32) {
    int i = b * 512 + t;  // 16384
    int f = i >> 6, h = i & 63;
    w1sh[i] = (_Float16)(lw1[f * 192 + h] + lw1[f * 192 + 64 + h] +
                         lw1[f * 192 + 128 + h]);
    b1h[i] = (_Float16)b1[f * 64 + h];
  } else if (b < 288) {
    int i = (b - 32) * 512 + t;  // 131072
    int f = i >> 9, n = (i >> 6) & 7, k = i & 63;
    w2t[i] = (__bf16)lw2[(f * 64 + k) * 8 + n];
  } else if (b < 544) {
    // pw2 [256 k][4096 col] f32 -> w2f fragment-major bf16
    const int bb = b - 288;           // 256 blocks: 4 k-tiles x 64 col-tiles
    const int tr = bb >> 6, tc = bb & 63;
    const int r0 = tr * 64, c0 = tc * 64;
    const int cc = t & 63, rq = t >> 6;  // rq 0..7
#pragma unroll
    for (int i = 0; i < 8; i++) {
      int rr = rq * 8 + i;
      tile[rr][cc] = pw2[(size_t)(r0 + rr) * 4096 + c0 + cc];
    }
    __syncthreads();
    const int rr2 = t & 63, cq = t >> 6;
    const int k = r0 + rr2;
#pragma unroll
    for (int i = 0; i < 8; i++) {
      int cc2 = cq * 8 + i;
      int col = c0 + cc2;
      int idx = (((col >> 4) * 8 + (k >> 5)) * 64 + (col & 15) * 4 +
                 ((k >> 3) & 3)) * 8 + (k & 7);
      w2f[idx] = (__bf16)tile[rr2][cc2];
    }
  } else {
    // weffQ[q(64)][n(256)][k(32)], q=f>>2, k=(f&3)*8+bucket ; W_eff = emb@W1
    const int f = b - 544;
    float* es = &tile[0][0];   // [8][128]
    float* red = es + 1024;    // [256][8]
    for (int i = t; i < 1024; i += 512) es[i] = emb[f * 1024 + i];
    __syncthreads();
    const int n = t & 255, dh = t >> 8;
    float s[8] = {0.f, 0.f, 0.f, 0.f, 0.f, 0.f, 0.f, 0.f};
    const float* pp = pw1 + (size_t)f * 32768 + (size_t)dh * 64 * 256 + n;
#pragma unroll 8
    for (int d = 0; d < 64; d++) {
      float wv = pp[(size_t)d * 256];
#pragma unroll
      for (int k = 0; k < 8; k++) s[k] += es[k * 128 + dh * 64 + d] * wv;
    }
    if (dh) {
#pragma unroll
      for (int k = 0; k < 8; k++) red[n * 8 + k] = s[k];
    }
    __syncthreads();
    if (!dh) {
      bf16x8 o;
#pragma unroll
      for (int k = 0; k < 8; k++) o[k] = (__bf16)(s[k] + red[n * 8 + k]);
      *(bf16x8*)&weffQ[((size_t)(f >> 2) * 256 + n) * 32 + (f & 3) * 8] = o;
    }
  }
}

// ---------------------------------------------------------------------------
// main fused kernel: grid = 64 row-tiles x 8 f-groups, 256 thr (4 waves).
// Wave owns 16 rows x 32 f. LDS-fed produce; 2-shfl softmax; Bq slice STAGED
// in LDS per block (4 waves read identical 16KB -> share via LDS, 4x less
// vmem-pipe traffic; T14 issue-early/write-late); SWAPPED z-GEMM -> f16x4.
// ---------------------------------------------------------------------------
__global__ __launch_bounds__(256, 2) void vg_main(
    const float* __restrict__ x,      // [4096][256]
    const _Float16* __restrict__ w1sh,// [256][64] f16
    const _Float16* __restrict__ b1h, // [256][64] f16
    const __bf16* __restrict__ w2t,   // [256][8][64]
    const float* __restrict__ b2l,    // [256][8]
    const float* __restrict__ tau,    // [256][8]
    const __bf16* __restrict__ weffQ, // [64][256][32]
    _Float16* __restrict__ zpart)     // [8][4096][256] f16
{
  __shared__ __align__(16) float xs[64][36];       // 32 f cols + pad
  __shared__ __align__(16) _Float16 ws1h[2048], wb1h[2048];
  __shared__ __align__(16) float wb2[256], wtau[256];
  __shared__ __align__(16) __bf16 w2l[256 * 72];   // 32f x 8n rows, pad->72
  __shared__ __align__(16) __bf16 w2s[8192];       // staged weffQ fq-slice 16KB

  const int g = blockIdx.x & 7;          // f-group
  const int r0 = (blockIdx.x >> 3) * 64;
  const int f0 = g * 32;
  const int t = threadIdx.x;
  const int w = t >> 6, l = t & 63, lo = l & 15, hi = l >> 4;

  for (int i = t; i < 2048; i += 256) {
    int rr = i >> 5, cc = i & 31;
    float v = x[(size_t)(r0 + rr) * 256 + f0 + cc];
    v = (v != v) ? 0.f : v;
    xs[rr][cc] = fminf(fmaxf(v, 0.f), 65536.f);
  }
  *(f16x8*)&ws1h[t * 8] = *(const f16x8*)&w1sh[f0 * 64 + t * 8];
  *(f16x8*)&wb1h[t * 8] = *(const f16x8*)&b1h[f0 * 64 + t * 8];
  {
    const __bf16* src = w2t + (size_t)f0 * 512;
    for (int c = t; c < 2048; c += 256) {
      int r = c >> 3, j = c & 7;
      *(bf16x8*)&w2l[r * 72 + j * 8] = *(const bf16x8*)&src[r * 64 + j * 8];
    }
  }
  wb2[t] = b2l[f0 * 8 + t];
  wtau[t] = tau[f0 * 8 + t];
  // stage fq=0 slice into w2s (linear copy; covered by the init barrier)
  {
    const __bf16* bp0 = weffQ + (size_t)(g * 8) * 8192 + w * 2048 + l * 8;
#pragma unroll
    for (int i = 0; i < 4; i++)
      *(uint4*)&w2s[w * 2048 + i * 512 + l * 8] = *(const uint4*)(bp0 + i * 512);
  }
  __syncthreads();  // init + stage(0) visible (r3 lesson)

  const int row = w * 16 + lo;
  const int lo7 = lo & 7;

  // ---- produce paq for f-quad fq (LDS-only); lane's f = f0+fq*4+hi
  auto produce = [&](int fq) -> bf16x8 {
    const float4 xq = *(const float4*)&xs[row][fq * 4];
    const float xr4[4] = {xq.x, xq.y, xq.z, xq.w};

    // A) 4 gacc chains (phase 1+2)
    f32x4 gacc4[4];
#pragma unroll
    for (int sub = 0; sub < 4; sub++) {
      const int fi = fq * 4 + sub;
      const float xr = xr4[sub];
      bf16x8 ha[2];
#pragma unroll
      for (int s = 0; s < 2; s++) {
        f16x8 wv = *(const f16x8*)(ws1h + fi * 64 + s * 32 + hi * 8);
        f16x8 bv = *(const f16x8*)(wb1h + fi * 64 + s * 32 + hi * 8);
#pragma unroll
        for (int j = 0; j < 8; j++) {
          float hv = lrelu(xr * (float)wv[j] + (float)bv[j]);
          ha[s][j] = (__bf16)hv;
        }
      }
      f32x4 gacc = {0.f, 0.f, 0.f, 0.f};
#pragma unroll
      for (int s = 0; s < 2; s++) {
        bf16x8 bw = *(const bf16x8*)&w2l[(fi * 8 + lo7) * 72 + s * 32 + hi * 8];
        gacc = MFMA16(bw, ha[s], gacc);
      }
      gacc4[sub] = gacc;
    }

    // B) pair softmax: exchange raw g (f16-packed, 2 shfls), then full
    // 8-bucket softmax in-lane; no max-sub (|g| bounded small).
    const int hb = hi & 1;
    const bool j2 = (hi & 2) != 0;
    f32x4 gA = j2 ? gacc4[2] : gacc4[0];
    f32x4 gB = j2 ? gacc4[3] : gacc4[1];
    const int sA = fq * 4 + (hi & 2);
    const float4 b2A = *(const float4*)&wb2[sA * 8 + hb * 4];
    const float4 tvA = *(const float4*)&wtau[sA * 8 + hb * 4];
    const float4 b2B = *(const float4*)&wb2[(sA + 1) * 8 + hb * 4];
    const float4 tvB = *(const float4*)&wtau[(sA + 1) * 8 + hb * 4];
    float gbA[4], gbB[4];
    gbA[0] = lrelu(gA[0] + b2A.x) * tvA.x;
    gbA[1] = lrelu(gA[1] + b2A.y) * tvA.y;
    gbA[2] = lrelu(gA[2] + b2A.z) * tvA.z;
    gbA[3] = lrelu(gA[3] + b2A.w) * tvA.w;
    gbB[0] = lrelu(gB[0] + b2B.x) * tvB.x;
    gbB[1] = lrelu(gB[1] + b2B.y) * tvB.y;
    gbB[2] = lrelu(gB[2] + b2B.z) * tvB.z;
    gbB[3] = lrelu(gB[3] + b2B.w) * tvB.w;
    float own[4], tx[4];
#pragma unroll
    for (int r = 0; r < 4; r++) {
      own[r] = hb ? gbB[r] : gbA[r];
      tx[r] = hb ? gbA[r] : gbB[r];
    }
    f16x4 th;
#pragma unroll
    for (int r = 0; r < 4; r++) th[r] = (_Float16)tx[r];
    uint2 tu = *(uint2*)&th, ru;
    ru.x = __shfl_xor((int)tu.x, 16);
    ru.y = __shfl_xor((int)tu.y, 16);
    f16x4 rh;
    *(uint2*)&rh = ru;
    float v8[8];
#pragma unroll
    for (int r = 0; r < 4; r++) {
      v8[r]     = hb ? (float)rh[r] : own[r];  // buckets 0-3
      v8[4 + r] = hb ? own[r] : (float)rh[r];  // buckets 4-7
    }
    float e8[8];
#pragma unroll
    for (int j = 0; j < 8; j++) e8[j] = __expf(v8[j]);
    float sum = ((e8[0] + e8[1]) + (e8[2] + e8[3])) +
                ((e8[4] + e8[5]) + (e8[6] + e8[7]));
    float inv = __builtin_amdgcn_rcpf(sum);
    bf16x8 paq;
#pragma unroll
    for (int j = 0; j < 8; j++) paq[j] = (__bf16)(e8[j] * inv);
    return paq;
  };

  f32x4 acc[16] = {};
  bf16x8 paq = produce(0);

  for (int fq = 0; fq < 8; fq++) {
    // A) issue next slice's global loads early (latency covered by B+C+D)
    uint4 st[4];
    if (fq < 7) {
      const __bf16* bp = weffQ + (size_t)(g * 8 + fq + 1) * 8192 + w * 2048 + l * 8;
#pragma unroll
      for (int i = 0; i < 4; i++) st[i] = *(const uint4*)(bp + i * 512);
    }

    // B) read Bq(fq) from staged LDS (1KB-contiguous, conflict-free)
    bf16x8 Bq[16];
#pragma unroll
    for (int n = 0; n < 16; n++)
      Bq[n] = *(const bf16x8*)&w2s[(n * 16 + lo) * 32 + hi * 8];

    // C) produce next paq (overlaps A's global latency and B's LDS latency)
    bf16x8 paq_next = {};
    if (fq < 7) paq_next = produce(fq + 1);

    // D) SWAPPED: lane(lo,hi) reg r = z[row=lo][col=n*16+hi*4+r]
#pragma unroll
    for (int n = 0; n < 16; n++) acc[n] = MFMA16(Bq[n], paq, acc[n]);
    paq = paq_next;

    // E) rotate stage: all waves done reading w2s(fq) -> write fq+1
    if (fq < 7) {
      __syncthreads();  // WAR: every wave's Bq reads complete
#pragma unroll
      for (int i = 0; i < 4; i++)
        *(uint4*)&w2s[w * 2048 + i * 512 + l * 8] = st[i];
      __syncthreads();  // staged slice visible to all waves
    }
  }

  // z store: lane writes 4 consecutive cols per n -> f16x4 (b64) stores
  _Float16* zp = zpart + (size_t)g * (4096 * 256) +
                 (size_t)(r0 + w * 16 + lo) * 256 + hi * 4;
#pragma unroll
  for (int n = 0; n < 16; n++) {
    f16x4 h;
#pragma unroll
    for (int r = 0; r < 4; r++) h[r] = (_Float16)acc[n][r];
    *(f16x4*)&zp[n * 16] = h;
  }
}

// ---------------------------------------------------------------------------
// z[b][n] = bf16(relu(sum over 8 f16 slabs + b1p[n])), fragment-major out
// ---------------------------------------------------------------------------
__global__ void vg_zred(const _Float16* __restrict__ zpart,
                        const float* __restrict__ b1p, __bf16* __restrict__ zf) {
  int i8 = (blockIdx.x * 256 + threadIdx.x) * 8;  // 1048576 total
  float s[8];
  {
    float4 ba = *(const float4*)&b1p[i8 & 255];
    float4 bb = *(const float4*)&b1p[(i8 & 255) + 4];
    s[0] = ba.x; s[1] = ba.y; s[2] = ba.z; s[3] = ba.w;
    s[4] = bb.x; s[5] = bb.y; s[6] = bb.z; s[7] = bb.w;
  }
#pragma unroll
  for (int g = 0; g < 8; g++) {
    uint4 v = *(const uint4*)&zpart[(size_t)g * 1048576 + i8];
    const _Float16* hp = (const _Float16*)&v;
#pragma unroll
    for (int j = 0; j < 8; j++) s[j] += (float)hp[j];
  }
  bf16x8 o;
#pragma unroll
  for (int j = 0; j < 8; j++) o[j] = (__bf16)fmaxf(s[j], 0.f);
  const int row = i8 >> 8, k0 = i8 & 255;
  const int idx = (((row >> 4) * 8 + (k0 >> 5)) * 64 + (row & 15) * 4 +
                   ((k0 >> 3) & 3)) * 8;
  *(bf16x8*)&zf[idx] = o;
}

// ---------------------------------------------------------------------------
// out = z @ W2 + b2 (r16 version): fragment-major loads; SWAPPED MFMA so each
// lane holds 4 consecutive out-cols -> float4 (dwordx4) stores.
// ---------------------------------------------------------------------------
__global__ __launch_bounds__(256, 2) void vg_out(
    const __bf16* __restrict__ zf,   // fragment-major [256 rb][8 ks][64][8]
    const __bf16* __restrict__ w2f,  // fragment-major [256 nb][8 ks][64][8]
    const float* __restrict__ b2,    // [4096]
    float* __restrict__ out)         // [4096][4096]
{
  const int m0 = (blockIdx.x & 31) * 128;
  const int n0 = (blockIdx.x >> 5) * 128;
  const int t = threadIdx.x, w = t >> 6, l = t & 63, lo = l & 15, hi = l >> 4;
  const int wm = w >> 1, wn = w & 1;  // 2x2 waves, 64x64 each
  const int fo = (lo * 4 + hi) * 8;   // fragment elem offset
  f32x4 acc[4][4] = {};
#pragma unroll
  for (int ks = 0; ks < 8; ks++) {
    bf16x8 A[4], Bq[4];
#pragma unroll
    for (int m = 0; m < 4; m++) {
      int rb = (m0 >> 4) + wm * 4 + m;
      A[m] = *(const bf16x8*)&zf[(rb * 8 + ks) * 512 + fo];
    }
#pragma unroll
    for (int n = 0; n < 4; n++) {
      int nb = (n0 >> 4) + wn * 4 + n;
      Bq[n] = *(const bf16x8*)&w2f[(nb * 8 + ks) * 512 + fo];
    }
    // SWAPPED: lane(lo,hi) reg r = out[row=lo][col = n*16 + hi*4 + r]
#pragma unroll
    for (int m = 0; m < 4; m++)
#pragma unroll
      for (int n = 0; n < 4; n++) acc[m][n] = MFMA16(Bq[n], A[m], acc[m][n]);
  }
#pragma unroll
  for (int m = 0; m < 4; m++) {
    const int row = m0 + wm * 64 + m * 16 + lo;
#pragma unroll
    for (int n = 0; n < 4; n++) {
      const int col = n0 + wn * 64 + n * 16 + hi * 4;
      float4 bv = *(const float4*)&b2[col];
      float4 v;
      v.x = acc[m][n][0] + bv.x;
      v.y = acc[m][n][1] + bv.y;
      v.z = acc[m][n][2] + bv.z;
      v.w = acc[m][n][3] + bv.w;
      *(float4*)&out[(size_t)row * 4096 + col] = v;
    }
  }
}

// ---------------------------------------------------------------------------
extern "C" void kernel_launch(void* const* d_in, const int* in_sizes, int n_in,
                              void* d_out, int out_size, void* d_ws, size_t ws_size,
                              hipStream_t stream) {
  const float* x   = (const float*)d_in[0];
  const float* lw1 = (const float*)d_in[1];
  const float* b1  = (const float*)d_in[2];
  const float* lw2 = (const float*)d_in[3];
  const float* b2l = (const float*)d_in[4];
  const float* tau = (const float*)d_in[5];
  const float* emb = (const float*)d_in[6];
  const float* pw1 = (const float*)d_in[7];
  const float* pb1 = (const float*)d_in[8];
  const float* pw2 = (const float*)d_in[9];
  const float* pb2 = (const float*)d_in[10];
  float* out = (float*)d_out;

  char* ws = (char*)d_ws;
  _Float16* w1sh = (_Float16*)(ws + 0);        //   32768 B
  _Float16* b1h  = (_Float16*)(ws + 32768);    //   32768 B
  __bf16* w2t    = (__bf16*)(ws + 65536);      //  262144 B
  __bf16* weffQ  = (__bf16*)(ws + 589824);     // 1048576 B
  __bf16* w2f    = (__bf16*)(ws + 1638400);    // 2097152 B fragment-major
  __bf16* zf     = (__bf16*)(ws + 3735552);    // 2097152 B fragment-major
  _Float16* zpart = (_Float16*)(ws + 5832704); // 16777216 B f16 (8 slabs)

  vg_prep<<<800, 512, 0, stream>>>(lw1, b1, lw2, pw2, emb, pw1,
                                   w1sh, b1h, w2t, w2f, weffQ);
  vg_main<<<512, 256, 0, stream>>>(x, w1sh, b1h, w2t, b2l, tau, weffQ, zpart);
  vg_zred<<<512, 256, 0, stream>>>(zpart, pb1, zf);
  vg_out<<<1024, 256, 0, stream>>>(zf, w2f, pb2, out);
}

// Round 24
// 69.369 us; speedup vs baseline: 1.0969x; 1.0969x over previous
//
#include <hip/hip_runtime.h>
#include <hip/hip_bf16.h>

typedef __bf16 bf16x8 __attribute__((ext_vector_type(8)));
typedef __bf16 bf16x4 __attribute__((ext_vector_type(4)));
typedef float  f32x4  __attribute__((ext_vector_type(4)));
typedef _Float16 f16x8 __attribute__((ext_vector_type(8)));
typedef _Float16 f16x4 __attribute__((ext_vector_type(4)));

#define MFMA16(a, b, c) __builtin_amdgcn_mfma_f32_16x16x32_bf16(a, b, c, 0, 0, 0)

__device__ __forceinline__ float lrelu(float v) { return fmaxf(v, 0.01f * v); }

// ---------------------------------------------------------------------------
// fused prep kernel (512 thr): b<32 w1s/b1->f16 ; b<288 w2t ; b<544 pw2->w2f
// fragment-major ; b<800 weff (d-split x2)
// ---------------------------------------------------------------------------
__global__ __launch_bounds__(512) void vg_prep(
    const float* __restrict__ lw1, const float* __restrict__ b1,
    const float* __restrict__ lw2, const float* __restrict__ pw2,
    const float* __restrict__ emb, const float* __restrict__ pw1,
    _Float16* __restrict__ w1sh, _Float16* __restrict__ b1h,
    __bf16* __restrict__ w2t, __bf16* __restrict__ w2f,
    __bf16* __restrict__ weffQ) {
  __shared__ float tile[64][65];  // 16640B; weff reuses as es(1024)+red(2048)
  const int b = blockIdx.x, t = threadIdx.x;
  if (b < 32) {
    int i = b * 512 + t;  // 16384
    int f = i >> 6, h = i & 63;
    w1sh[i] = (_Float16)(lw1[f * 192 + h] + lw1[f * 192 + 64 + h] +
                         lw1[f * 192 + 128 + h]);
    b1h[i] = (_Float16)b1[f * 64 + h];
  } else if (b < 288) {
    int i = (b - 32) * 512 + t;  // 131072
    int f = i >> 9, n = (i >> 6) & 7, k = i & 63;
    w2t[i] = (__bf16)lw2[(f * 64 + k) * 8 + n];
  } else if (b < 544) {
    // pw2 [256 k][4096 col] f32 -> w2f fragment-major bf16
    const int bb = b - 288;           // 256 blocks: 4 k-tiles x 64 col-tiles
    const int tr = bb >> 6, tc = bb & 63;
    const int r0 = tr * 64, c0 = tc * 64;
    const int cc = t & 63, rq = t >> 6;  // rq 0..7
#pragma unroll
    for (int i = 0; i < 8; i++) {
      int rr = rq * 8 + i;
      tile[rr][cc] = pw2[(size_t)(r0 + rr) * 4096 + c0 + cc];
    }
    __syncthreads();
    const int rr2 = t & 63, cq = t >> 6;
    const int k = r0 + rr2;
#pragma unroll
    for (int i = 0; i < 8; i++) {
      int cc2 = cq * 8 + i;
      int col = c0 + cc2;
      int idx = (((col >> 4) * 8 + (k >> 5)) * 64 + (col & 15) * 4 +
                 ((k >> 3) & 3)) * 8 + (k & 7);
      w2f[idx] = (__bf16)tile[rr2][cc2];
    }
  } else {
    // weffQ[q(64)][n(256)][k(32)], q=f>>2, k=(f&3)*8+bucket ; W_eff = emb@W1
    const int f = b - 544;
    float* es = &tile[0][0];   // [8][128]
    float* red = es + 1024;    // [256][8]
    for (int i = t; i < 1024; i += 512) es[i] = emb[f * 1024 + i];
    __syncthreads();
    const int n = t & 255, dh = t >> 8;
    float s[8] = {0.f, 0.f, 0.f, 0.f, 0.f, 0.f, 0.f, 0.f};
    const float* pp = pw1 + (size_t)f * 32768 + (size_t)dh * 64 * 256 + n;
#pragma unroll 8
    for (int d = 0; d < 64; d++) {
      float wv = pp[(size_t)d * 256];
#pragma unroll
      for (int k = 0; k < 8; k++) s[k] += es[k * 128 + dh * 64 + d] * wv;
    }
    if (dh) {
#pragma unroll
      for (int k = 0; k < 8; k++) red[n * 8 + k] = s[k];
    }
    __syncthreads();
    if (!dh) {
      bf16x8 o;
#pragma unroll
      for (int k = 0; k < 8; k++) o[k] = (__bf16)(s[k] + red[n * 8 + k]);
      *(bf16x8*)&weffQ[((size_t)(f >> 2) * 256 + n) * 32 + (f & 3) * 8] = o;
    }
  }
}

// ---------------------------------------------------------------------------
// main fused kernel (r16/r22 version): grid = 64 row-tiles x 8 f-groups,
// 256 thr. Wave owns 16 rows x 32 f. LDS-fed produce; 2-shfl softmax;
// coalesced weffQ Bq; SWAPPED z-GEMM -> f16x4 z stores.
// ---------------------------------------------------------------------------
__global__ __launch_bounds__(256, 2) void vg_main(
    const float* __restrict__ x,      // [4096][256]
    const _Float16* __restrict__ w1sh,// [256][64] f16
    const _Float16* __restrict__ b1h, // [256][64] f16
    const __bf16* __restrict__ w2t,   // [256][8][64]
    const float* __restrict__ b2l,    // [256][8]
    const float* __restrict__ tau,    // [256][8]
    const __bf16* __restrict__ weffQ, // [64][256][32]
    _Float16* __restrict__ zpart)     // [8][4096][256] f16
{
  __shared__ __align__(16) float xs[64][36];       // 32 f cols + pad
  __shared__ __align__(16) _Float16 ws1h[2048], wb1h[2048];
  __shared__ __align__(16) float wb2[256], wtau[256];
  __shared__ __align__(16) __bf16 w2l[256 * 72];   // 32f x 8n rows, pad->72

  const int g = blockIdx.x & 7;          // f-group
  const int r0 = (blockIdx.x >> 3) * 64;
  const int f0 = g * 32;
  const int t = threadIdx.x;
  const int w = t >> 6, l = t & 63, lo = l & 15, hi = l >> 4;

  for (int i = t; i < 2048; i += 256) {
    int rr = i >> 5, cc = i & 31;
    float v = x[(size_t)(r0 + rr) * 256 + f0 + cc];
    v = (v != v) ? 0.f : v;
    xs[rr][cc] = fminf(fmaxf(v, 0.f), 65536.f);
  }
  *(f16x8*)&ws1h[t * 8] = *(const f16x8*)&w1sh[f0 * 64 + t * 8];
  *(f16x8*)&wb1h[t * 8] = *(const f16x8*)&b1h[f0 * 64 + t * 8];
  {
    const __bf16* src = w2t + (size_t)f0 * 512;
    for (int c = t; c < 2048; c += 256) {
      int r = c >> 3, j = c & 7;
      *(bf16x8*)&w2l[r * 72 + j * 8] = *(const bf16x8*)&src[r * 64 + j * 8];
    }
  }
  wb2[t] = b2l[f0 * 8 + t];
  wtau[t] = tau[f0 * 8 + t];
  __syncthreads();  // init visible (r3 lesson); only barrier

  const int row = w * 16 + lo;
  const int lo7 = lo & 7;

  // ---- produce paq for f-quad fq (LDS-only); lane's f = f0+fq*4+hi
  auto produce = [&](int fq) -> bf16x8 {
    const float4 xq = *(const float4*)&xs[row][fq * 4];
    const float xr4[4] = {xq.x, xq.y, xq.z, xq.w};

    // A) 4 gacc chains (phase 1+2)
    f32x4 gacc4[4];
#pragma unroll
    for (int sub = 0; sub < 4; sub++) {
      const int fi = fq * 4 + sub;
      const float xr = xr4[sub];
      bf16x8 ha[2];
#pragma unroll
      for (int s = 0; s < 2; s++) {
        f16x8 wv = *(const f16x8*)(ws1h + fi * 64 + s * 32 + hi * 8);
        f16x8 bv = *(const f16x8*)(wb1h + fi * 64 + s * 32 + hi * 8);
#pragma unroll
        for (int j = 0; j < 8; j++) {
          float hv = lrelu(xr * (float)wv[j] + (float)bv[j]);
          ha[s][j] = (__bf16)hv;
        }
      }
      f32x4 gacc = {0.f, 0.f, 0.f, 0.f};
#pragma unroll
      for (int s = 0; s < 2; s++) {
        bf16x8 bw = *(const bf16x8*)&w2l[(fi * 8 + lo7) * 72 + s * 32 + hi * 8];
        gacc = MFMA16(bw, ha[s], gacc);
      }
      gacc4[sub] = gacc;
    }

    // B) pair softmax: exchange raw g (f16-packed, 2 shfls), then full
    // 8-bucket softmax in-lane; no max-sub (|g| bounded small).
    const int hb = hi & 1;
    const bool j2 = (hi & 2) != 0;
    f32x4 gA = j2 ? gacc4[2] : gacc4[0];
    f32x4 gB = j2 ? gacc4[3] : gacc4[1];
    const int sA = fq * 4 + (hi & 2);
    const float4 b2A = *(const float4*)&wb2[sA * 8 + hb * 4];
    const float4 tvA = *(const float4*)&wtau[sA * 8 + hb * 4];
    const float4 b2B = *(const float4*)&wb2[(sA + 1) * 8 + hb * 4];
    const float4 tvB = *(const float4*)&wtau[(sA + 1) * 8 + hb * 4];
    float gbA[4], gbB[4];
    gbA[0] = lrelu(gA[0] + b2A.x) * tvA.x;
    gbA[1] = lrelu(gA[1] + b2A.y) * tvA.y;
    gbA[2] = lrelu(gA[2] + b2A.z) * tvA.z;
    gbA[3] = lrelu(gA[3] + b2A.w) * tvA.w;
    gbB[0] = lrelu(gB[0] + b2B.x) * tvB.x;
    gbB[1] = lrelu(gB[1] + b2B.y) * tvB.y;
    gbB[2] = lrelu(gB[2] + b2B.z) * tvB.z;
    gbB[3] = lrelu(gB[3] + b2B.w) * tvB.w;
    float own[4], tx[4];
#pragma unroll
    for (int r = 0; r < 4; r++) {
      own[r] = hb ? gbB[r] : gbA[r];
      tx[r] = hb ? gbA[r] : gbB[r];
    }
    f16x4 th;
#pragma unroll
    for (int r = 0; r < 4; r++) th[r] = (_Float16)tx[r];
    uint2 tu = *(uint2*)&th, ru;
    ru.x = __shfl_xor((int)tu.x, 16);
    ru.y = __shfl_xor((int)tu.y, 16);
    f16x4 rh;
    *(uint2*)&rh = ru;
    float v8[8];
#pragma unroll
    for (int r = 0; r < 4; r++) {
      v8[r]     = hb ? (float)rh[r] : own[r];  // buckets 0-3
      v8[4 + r] = hb ? own[r] : (float)rh[r];  // buckets 4-7
    }
    float e8[8];
#pragma unroll
    for (int j = 0; j < 8; j++) e8[j] = __expf(v8[j]);
    float sum = ((e8[0] + e8[1]) + (e8[2] + e8[3])) +
                ((e8[4] + e8[5]) + (e8[6] + e8[7]));
    float inv = __builtin_amdgcn_rcpf(sum);
    bf16x8 paq;
#pragma unroll
    for (int j = 0; j < 8; j++) paq[j] = (__bf16)(e8[j] * inv);
    return paq;
  };

  f32x4 acc[16] = {};
  bf16x8 paq = produce(0);

  for (int fq = 0; fq < 8; fq++) {
    // issue all 16 B loads first (coalesced 1KB spans); covered by produce
    const __bf16* bp = weffQ + (size_t)(g * 8 + fq) * 8192;
    bf16x8 Bq[16];
#pragma unroll
    for (int n = 0; n < 16; n++)
      Bq[n] = *(const bf16x8*)&bp[(n * 16 + lo) * 32 + hi * 8];

    bf16x8 paq_next = {};
    if (fq < 7) paq_next = produce(fq + 1);

    // SWAPPED operands: lane(lo,hi) reg r = z[row=lo][col=n*16+hi*4+r]
#pragma unroll
    for (int n = 0; n < 16; n++) acc[n] = MFMA16(Bq[n], paq, acc[n]);
    paq = paq_next;
  }

  // z store: lane writes 4 consecutive cols per n -> f16x4 (b64) stores
  _Float16* zp = zpart + (size_t)g * (4096 * 256) +
                 (size_t)(r0 + w * 16 + lo) * 256 + hi * 4;
#pragma unroll
  for (int n = 0; n < 16; n++) {
    f16x4 h;
#pragma unroll
    for (int r = 0; r < 4; r++) h[r] = (_Float16)acc[n][r];
    *(f16x4*)&zp[n * 16] = h;
  }
}

// ---------------------------------------------------------------------------
// z[b][n] = bf16(relu(sum over 8 f16 slabs + b1p[n])), fragment-major out
// ---------------------------------------------------------------------------
__global__ void vg_zred(const _Float16* __restrict__ zpart,
                        const float* __restrict__ b1p, __bf16* __restrict__ zf) {
  int i8 = (blockIdx.x * 256 + threadIdx.x) * 8;  // 1048576 total
  float s[8];
  {
    float4 ba = *(const float4*)&b1p[i8 & 255];
    float4 bb = *(const float4*)&b1p[(i8 & 255) + 4];
    s[0] = ba.x; s[1] = ba.y; s[2] = ba.z; s[3] = ba.w;
    s[4] = bb.x; s[5] = bb.y; s[6] = bb.z; s[7] = bb.w;
  }
#pragma unroll
  for (int g = 0; g < 8; g++) {
    uint4 v = *(const uint4*)&zpart[(size_t)g * 1048576 + i8];
    const _Float16* hp = (const _Float16*)&v;
#pragma unroll
    for (int j = 0; j < 8; j++) s[j] += (float)hp[j];
  }
  bf16x8 o;
#pragma unroll
  for (int j = 0; j < 8; j++) o[j] = (__bf16)fmaxf(s[j], 0.f);
  const int row = i8 >> 8, k0 = i8 & 255;
  const int idx = (((row >> 4) * 8 + (k0 >> 5)) * 64 + (row & 15) * 4 +
                   ((k0 >> 3) & 3)) * 8;
  *(bf16x8*)&zf[idx] = o;
}

// ---------------------------------------------------------------------------
// out = z @ W2 + b2 (r16 version): fragment-major loads; SWAPPED MFMA so each
// lane holds 4 consecutive out-cols -> float4 (dwordx4) stores.
// ---------------------------------------------------------------------------
__global__ __launch_bounds__(256, 2) void vg_out(
    const __bf16* __restrict__ zf,   // fragment-major [256 rb][8 ks][64][8]
    const __bf16* __restrict__ w2f,  // fragment-major [256 nb][8 ks][64][8]
    const float* __restrict__ b2,    // [4096]
    float* __restrict__ out)         // [4096][4096]
{
  const int m0 = (blockIdx.x & 31) * 128;
  const int n0 = (blockIdx.x >> 5) * 128;
  const int t = threadIdx.x, w = t >> 6, l = t & 63, lo = l & 15, hi = l >> 4;
  const int wm = w >> 1, wn = w & 1;  // 2x2 waves, 64x64 each
  const int fo = (lo * 4 + hi) * 8;   // fragment elem offset
  f32x4 acc[4][4] = {};
#pragma unroll
  for (int ks = 0; ks < 8; ks++) {
    bf16x8 A[4], Bq[4];
#pragma unroll
    for (int m = 0; m < 4; m++) {
      int rb = (m0 >> 4) + wm * 4 + m;
      A[m] = *(const bf16x8*)&zf[(rb * 8 + ks) * 512 + fo];
    }
#pragma unroll
    for (int n = 0; n < 4; n++) {
      int nb = (n0 >> 4) + wn * 4 + n;
      Bq[n] = *(const bf16x8*)&w2f[(nb * 8 + ks) * 512 + fo];
    }
    // SWAPPED: lane(lo,hi) reg r = out[row=lo][col = n*16 + hi*4 + r]
#pragma unroll
    for (int m = 0; m < 4; m++)
#pragma unroll
      for (int n = 0; n < 4; n++) acc[m][n] = MFMA16(Bq[n], A[m], acc[m][n]);
  }
#pragma unroll
  for (int m = 0; m < 4; m++) {
    const int row = m0 + wm * 64 + m * 16 + lo;
#pragma unroll
    for (int n = 0; n < 4; n++) {
      const int col = n0 + wn * 64 + n * 16 + hi * 4;
      float4 bv = *(const float4*)&b2[col];
      float4 v;
      v.x = acc[m][n][0] + bv.x;
      v.y = acc[m][n][1] + bv.y;
      v.z = acc[m][n][2] + bv.z;
      v.w = acc[m][n][3] + bv.w;
      *(float4*)&out[(size_t)row * 4096 + col] = v;
    }
  }
}

// ---------------------------------------------------------------------------
extern "C" void kernel_launch(void* const* d_in, const int* in_sizes, int n_in,
                              void* d_out, int out_size, void* d_ws, size_t ws_size,
                              hipStream_t stream) {
  const float* x   = (const float*)d_in[0];
  const float* lw1 = (const float*)d_in[1];
  const float* b1  = (const float*)d_in[2];
  const float* lw2 = (const float*)d_in[3];
  const float* b2l = (const float*)d_in[4];
  const float* tau = (const float*)d_in[5];
  const float* emb = (const float*)d_in[6];
  const float* pw1 = (const float*)d_in[7];
  const float* pb1 = (const float*)d_in[8];
  const float* pw2 = (const float*)d_in[9];
  const float* pb2 = (const float*)d_in[10];
  float* out = (float*)d_out;

  char* ws = (char*)d_ws;
  _Float16* w1sh = (_Float16*)(ws + 0);        //   32768 B
  _Float16* b1h  = (_Float16*)(ws + 32768);    //   32768 B
  __bf16* w2t    = (__bf16*)(ws + 65536);      //  262144 B
  __bf16* weffQ  = (__bf16*)(ws + 589824);     // 1048576 B
  __bf16* w2f    = (__bf16*)(ws + 1638400);    // 2097152 B fragment-major
  __bf16* zf     = (__bf16*)(ws + 3735552);    // 2097152 B fragment-major
  _Float16* zpart = (_Float16*)(ws + 5832704); // 16777216 B f16 (8 slabs)

  vg_prep<<<800, 512, 0, stream>>>(lw1, b1, lw2, pw2, emb, pw1,
                                   w1sh, b1h, w2t, w2f, weffQ);
  vg_main<<<512, 256, 0, stream>>>(x, w1sh, b1h, w2t, b2l, tau, weffQ, zpart);
  vg_zred<<<512, 256, 0, stream>>>(zpart, pb1, zf);
  vg_out<<<1024, 256, 0, stream>>>(zf, w2f, pb2, out);
}